// Round 4
// baseline (989.494 us; speedup 1.0000x reference)
//
#include <hip/hip_runtime.h>
#include <hip/hip_bf16.h>
#include <cstdint>

#define NTOK 4096
#define DMODEL 2048
#define NEXP 8
#define HR 1408
#define HSHARED 2816
#define MAXT128 72

#define KG_SH 1408                        // 44 n x 32 m shared gateup jobs
#define KG_TOTAL (KG_SH + 22 * MAXT128)   // 2992
#define CVT1_TOTAL 7040                   // wd: 8*704, sd: 1408
#define KD_GRID (512 + 16 * MAXT128)      // 1664
#define PREP_GRID (512 + 11264 + 2816)    // router + gu-cvt + s-cvt
#define STRIPES 499                       // 499*6>=2992, 499*15>=7040

typedef __attribute__((ext_vector_type(8))) short bf16x8;
typedef __attribute__((ext_vector_type(4))) float f32x4;

__device__ inline unsigned short f2b(float f) {
    unsigned u = __float_as_uint(f);
    u += 0x7fffu + ((u >> 16) & 1u);   // RNE
    return (unsigned short)(u >> 16);
}
__device__ inline unsigned pack2(float a, float b) {
    return (unsigned)f2b(a) | ((unsigned)f2b(b) << 16);
}

// async global->LDS, 16B/lane; dest = lds(wave-uniform) + lane*16
__device__ __forceinline__ void gll16(unsigned short* lds, const unsigned short* g) {
    __builtin_amdgcn_global_load_lds(
        (__attribute__((address_space(1))) void*)g,
        (__attribute__((address_space(3))) void*)lds, 16, 0, 0);
}

// fp32 [K,N] src -> bf16 [N][dstride] dst, one 64x64 tile; T is caller LDS
__device__ __forceinline__ void tcvt_tile(const float* __restrict__ src,
                                          unsigned short* __restrict__ dst,
                                          int N, int dstride, int n0, int k0,
                                          unsigned short (*T)[72]) {
    int t = threadIdx.x;
    int kr = t >> 4, nc = (t & 15) * 4;
#pragma unroll
    for (int i = 0; i < 4; i++) {
        int k = kr + i * 16;
        float4 v = *(const float4*)(src + (size_t)(k0 + k) * N + n0 + nc);
        T[k][nc] = f2b(v.x); T[k][nc + 1] = f2b(v.y);
        T[k][nc + 2] = f2b(v.z); T[k][nc + 3] = f2b(v.w);
    }
    __syncthreads();
    int nr = t >> 3, kc = (t & 7) * 8;
#pragma unroll
    for (int j = 0; j < 2; j++) {
        int n = nr + j * 32;
        unsigned short tmp[8];
#pragma unroll
        for (int u = 0; u < 8; u++) tmp[u] = T[kc + u][n];
        *(uint4*)(dst + (size_t)(n0 + n) * dstride + k0 + kc) = *(uint4*)tmp;
    }
}

// ====== prep: router (+x cvt) merged with gate/up + shared weight cvt ======
__global__ __launch_bounds__(256) void k_prep(
    const float* __restrict__ x, const float* __restrict__ rw,
    const float* __restrict__ wg, const float* __restrict__ wu,
    const float* __restrict__ sg, const float* __restrict__ su,
    unsigned short* __restrict__ xb,
    unsigned short* __restrict__ wgT, unsigned short* __restrict__ wuT,
    unsigned short* __restrict__ sgT, unsigned short* __restrict__ suT,
    int* __restrict__ topi, float* __restrict__ topw, int* __restrict__ counts) {
    __shared__ unsigned short pT[64][72];
    int bx = blockIdx.x;
    if (bx >= 512) {
        int t = bx - 512;
        if (t < 11264) {           // wg/wu: [2048,1408] -> [1408,2048]
            int z = t / 704, rem = t % 704;
            int n_t = rem % 22, k_t = rem / 22;
            const float* src = (z < 8 ? wg : wu) + (size_t)(z & 7) * DMODEL * HR;
            unsigned short* dst = (z < 8 ? wgT : wuT) + (size_t)(z & 7) * HR * DMODEL;
            tcvt_tile(src, dst, HR, DMODEL, n_t * 64, k_t * 64, pT);
        } else {                   // sg/su: [2048,2816] -> [2816,2048]
            int t2 = t - 11264;
            int z = t2 / 1408, rem = t2 % 1408;
            int n_t = rem % 44, k_t = rem / 44;
            tcvt_tile(z ? su : sg, z ? suT : sgT, HSHARED, DMODEL,
                      n_t * 64, k_t * 64, pT);
        }
        return;
    }
    // router, 2 tokens per wave; rw read from L2 (64 KB, hot)
    int tid = threadIdx.x;
    int wv = tid >> 6, lane = tid & 63;
#pragma unroll
    for (int tk = 0; tk < 2; tk++) {
        int tok = bx * 8 + wv * 2 + tk;
        const float* xr = x + (size_t)tok * DMODEL;
        unsigned short* xbr = xb + (size_t)tok * DMODEL;
        float s[NEXP] = {0.f,0.f,0.f,0.f,0.f,0.f,0.f,0.f};
#pragma unroll
        for (int i = 0; i < 8; i++) {
            int d = i * 256 + lane * 4;
            float4 xv = *(const float4*)(xr + d);
            uint2 p; p.x = pack2(xv.x, xv.y); p.y = pack2(xv.z, xv.w);
            *(uint2*)(xbr + d) = p;
#pragma unroll
            for (int e = 0; e < NEXP; e++) {
                float4 w = *(const float4*)&rw[e * DMODEL + d];
                s[e] = fmaf(xv.x, w.x, s[e]); s[e] = fmaf(xv.y, w.y, s[e]);
                s[e] = fmaf(xv.z, w.z, s[e]); s[e] = fmaf(xv.w, w.w, s[e]);
            }
        }
#pragma unroll
        for (int e = 0; e < NEXP; e++)
#pragma unroll
            for (int o = 32; o > 0; o >>= 1) s[e] += __shfl_xor(s[e], o, 64);
        if (lane == 0) {
            int i1 = 0;
#pragma unroll
            for (int e = 1; e < NEXP; e++) if (s[e] > s[i1]) i1 = e;
            int i2 = (i1 == 0) ? 1 : 0;
#pragma unroll
            for (int e = 0; e < NEXP; e++) if (e != i1 && s[e] > s[i2]) i2 = e;
            float mx = s[0];
#pragma unroll
            for (int e = 1; e < NEXP; e++) mx = fmaxf(mx, s[e]);
            float den = 0.f, ex[NEXP];
#pragma unroll
            for (int e = 0; e < NEXP; e++) { ex[e] = __expf(s[e] - mx); den += ex[e]; }
            float v1 = ex[i1] / den, v2 = ex[i2] / den;
            float inv = 1.f / (v1 + v2 + 1e-20f);
            topi[2 * tok] = i1; topi[2 * tok + 1] = i2;
            topw[2 * tok] = v1 * inv; topw[2 * tok + 1] = v2 * inv;
            atomicAdd(&counts[i1], 1); atomicAdd(&counts[i2], 1);
        }
    }
}

__global__ void k_scan(int* counts, int* offsets, int* cursors, int* ntiles,
                       int* tile_e, int* tile_r) {
    if (threadIdx.x == 0 && blockIdx.x == 0) {
        int off = 0, nt = 0;
        for (int e = 0; e < NEXP; e++) {
            offsets[e] = off; cursors[e] = off;
            int c = counts[e];
            for (int r = 0; r < c; r += 128) { tile_e[nt] = e; tile_r[nt] = r; nt++; }
            off += c;
        }
        ntiles[0] = nt;
    }
}

__global__ __launch_bounds__(256) void k_fill(const int* __restrict__ topi,
                                              const float* __restrict__ topw,
                                              int* cursors, int* at, float* aw) {
    int t = blockIdx.x * 256 + threadIdx.x;
    if (t >= NTOK) return;
#pragma unroll
    for (int k = 0; k < 2; k++) {
        int e = topi[2 * t + k];
        int pos = atomicAdd(&cursors[e], 1);
        at[pos] = t; aw[pos] = topw[2 * t + k];
    }
}

// ====== phase 1: gateup GEMMs (shared+routed) interleaved with wd/sd cvt =====
__global__ __launch_bounds__(256) void k_main1(
    const unsigned short* __restrict__ xb,
    const unsigned short* __restrict__ sgT, const unsigned short* __restrict__ suT,
    const unsigned short* __restrict__ wgT, const unsigned short* __restrict__ wuT,
    const float* __restrict__ wd, const float* __restrict__ sd,
    unsigned short* __restrict__ wdT, unsigned short* __restrict__ sdT,
    const int* __restrict__ tile_e, const int* __restrict__ tile_r,
    const int* __restrict__ offsets, const int* __restrict__ counts,
    const int* __restrict__ ntiles, const int* __restrict__ at,
    unsigned short* __restrict__ h_s, unsigned short* __restrict__ h_r,
    int kg_count, int cvt_count) {
    __shared__ __align__(16) unsigned short smem[16384];   // 32 KB
    int bx = blockIdx.x;
    int kgid = -1, cvid = -1;
    if (cvt_count == 0) kgid = bx;
    else if (kg_count == 0) cvid = bx;
    else {
        int s = bx / 21, r = bx % 21;
        if (r < 6) { int id = s * 6 + r; if (id >= kg_count) return; kgid = id; }
        else       { int id = s * 15 + (r - 6); if (id >= cvt_count) return; cvid = id; }
    }

    if (cvid >= 0) {   // wd/sd transpose-convert tile
        unsigned short (*T)[72] = (unsigned short(*)[72])smem;
        if (cvid < 5632) {    // wd e: [1408,2048] -> [2048,1408]
            int e = cvid / 704, rem = cvid % 704;
            int n_t = rem % 32, k_t = rem / 32;
            tcvt_tile(wd + (size_t)e * HR * DMODEL, wdT + (size_t)e * DMODEL * HR,
                      DMODEL, HR, n_t * 64, k_t * 64, T);
        } else {              // sd: [2816,2048] -> [2048,2816]
            int c2 = cvid - 5632;
            int n_t = c2 % 32, k_t = c2 / 32;
            tcvt_tile(sd, sdT, DMODEL, HSHARED, n_t * 64, k_t * 64, T);
        }
        return;
    }

    // ---- gateup job ----
    unsigned short* As = smem;            // 8192 ushort
    unsigned short* Bgs = smem + 8192;    // 4096
    unsigned short* Bus = smem + 12288;   // 4096
    int m0, mcnt, n0, Hld;
    const unsigned short *Bg, *Bu;
    unsigned short* ho;
    bool gath;
    if (kgid < KG_SH) {            // shared, n-major: 44 n x 32 m
        gath = false;
        n0 = (kgid >> 5) * 64;
        m0 = (kgid & 31) * 128; mcnt = 128;
        Bg = sgT; Bu = suT; Hld = HSHARED; ho = h_s;
    } else {                       // routed, n-major: 22 n x 72 tile slots
        int id2 = kgid - KG_SH;
        int tile = id2 % MAXT128;
        if (tile >= ntiles[0]) return;
        gath = true;
        n0 = (id2 / MAXT128) * 64;
        int e = tile_e[tile], ro = tile_r[tile];
        m0 = offsets[e] + ro;
        mcnt = counts[e] - ro; if (mcnt > 128) mcnt = 128;
        size_t wo = (size_t)e * HR * DMODEL;
        Bg = wgT + wo; Bu = wuT + wo; Hld = HR; ho = h_r;
    }

    int tid = threadIdx.x;
    int wv = tid >> 6, lane = tid & 63;
    int rbase = tid >> 3;
    int kc = (tid & 7) ^ ((tid >> 3) & 7);   // XOR-swizzled chunk
    const unsigned short* arp[4];
#pragma unroll
    for (int j = 0; j < 4; j++) {
        int row = j * 32 + rbase;
        int cl = row < mcnt ? row : mcnt - 1;
        int grow = gath ? at[m0 + cl] : (m0 + cl);
        arp[j] = xb + (size_t)grow * DMODEL + kc * 8;
    }
    const unsigned short* bgp[2];
    const unsigned short* bup[2];
#pragma unroll
    for (int j = 0; j < 2; j++) {
        int row = j * 32 + rbase;
        bgp[j] = Bg + (size_t)(n0 + row) * DMODEL + kc * 8;
        bup[j] = Bu + (size_t)(n0 + row) * DMODEL + kc * 8;
    }
    unsigned short* a_l = As + (wv << 6) * 8;
    unsigned short* g_l = Bgs + (wv << 6) * 8;
    unsigned short* u_l = Bus + (wv << 6) * 8;

    int fr = lane & 15, quad = lane >> 4, sw = fr & 7;
    int wm = (wv & 1) << 6, wn = (wv >> 1) << 5;

    f32x4 accg[4][2] = {};
    f32x4 accu[4][2] = {};

    for (int k0 = 0; k0 < DMODEL; k0 += 64) {
        __syncthreads();
#pragma unroll
        for (int j = 0; j < 4; j++) gll16(a_l + j * 2048, arp[j] + k0);
#pragma unroll
        for (int j = 0; j < 2; j++) {
            gll16(g_l + j * 2048, bgp[j] + k0);
            gll16(u_l + j * 2048, bup[j] + k0);
        }
        __syncthreads();
#pragma unroll
        for (int s = 0; s < 2; s++) {
            int off = (((s << 2) + quad) ^ sw) << 3;
            bf16x8 a[4], g[2], u[2];
#pragma unroll
            for (int tm = 0; tm < 4; tm++)
                a[tm] = *(const bf16x8*)&As[(wm + tm * 16 + fr) * 64 + off];
#pragma unroll
            for (int tn = 0; tn < 2; tn++) {
                int rb = (wn + tn * 16 + fr) * 64 + off;
                g[tn] = *(const bf16x8*)&Bgs[rb];
                u[tn] = *(const bf16x8*)&Bus[rb];
            }
#pragma unroll
            for (int tm = 0; tm < 4; tm++)
#pragma unroll
                for (int tn = 0; tn < 2; tn++) {
                    accg[tm][tn] = __builtin_amdgcn_mfma_f32_16x16x32_bf16(a[tm], g[tn], accg[tm][tn], 0, 0, 0);
                    accu[tm][tn] = __builtin_amdgcn_mfma_f32_16x16x32_bf16(a[tm], u[tn], accu[tm][tn], 0, 0, 0);
                }
        }
    }
    // epilogue: silu(g)*u -> bf16 via LDS (pad 72), then b128 stores
    __syncthreads();
#pragma unroll
    for (int tm = 0; tm < 4; tm++)
#pragma unroll
        for (int r = 0; r < 4; r++) {
            int row = wm + tm * 16 + (quad << 2) + r;
#pragma unroll
            for (int tn = 0; tn < 2; tn++) {
                float gv = accg[tm][tn][r], uv = accu[tm][tn][r];
                float hv = (gv / (1.f + __expf(-gv))) * uv;
                smem[row * 72 + wn + tn * 16 + fr] = f2b(hv);
            }
        }
    __syncthreads();
    int tr = tid >> 3, tc = (tid & 7) << 3;
#pragma unroll
    for (int i = 0; i < 4; i++) {
        int row = i * 32 + tr;
        if (row < mcnt)
            *(uint4*)&ho[(size_t)(m0 + row) * Hld + n0 + tc] =
                *(const uint4*)&smem[row * 72 + tc];
    }
}

// ====== phase 2: down GEMM (shared + routed), atomic epilogue ======
__global__ __launch_bounds__(256) void kd_all(
    const unsigned short* __restrict__ h_s, const unsigned short* __restrict__ h_r,
    const unsigned short* __restrict__ sdT, const unsigned short* __restrict__ wdT,
    const int* __restrict__ tile_e, const int* __restrict__ tile_r,
    const int* __restrict__ offsets, const int* __restrict__ counts,
    const int* __restrict__ ntiles, const int* __restrict__ at,
    const float* __restrict__ aw, float* __restrict__ out) {
    int j = blockIdx.x;
    int m0, mcnt, n0, Kd;
    const unsigned short *Ab, *Bb;
    bool gath;
    if (j < 512) {                 // shared, n-major: 16 n x 32 m
        gath = false;
        n0 = (j >> 5) * 128;
        m0 = (j & 31) * 128; mcnt = 128;
        Ab = h_s; Bb = sdT; Kd = HSHARED;
    } else {                       // routed, n-major: 16 n x 72 tiles
        int j2 = j - 512;
        int tile = j2 % MAXT128;
        if (tile >= ntiles[0]) return;
        gath = true;
        n0 = (j2 / MAXT128) * 128;
        int e = tile_e[tile], ro = tile_r[tile];
        m0 = offsets[e] + ro;
        mcnt = counts[e] - ro; if (mcnt > 128) mcnt = 128;
        Ab = h_r; Bb = wdT + (size_t)e * DMODEL * HR;
        Kd = HR;
    }

    __shared__ __align__(16) unsigned short As[128 * 64];
    __shared__ __align__(16) unsigned short Bs[128 * 64];

    int tid = threadIdx.x;
    int wv = tid >> 6, lane = tid & 63;
    int rbase = tid >> 3;
    int kc = (tid & 7) ^ ((tid >> 3) & 7);
    const unsigned short* arp[4];
    const unsigned short* brp[4];
#pragma unroll
    for (int j2 = 0; j2 < 4; j2++) {
        int row = j2 * 32 + rbase;
        int cl = row < mcnt ? row : mcnt - 1;
        arp[j2] = Ab + (size_t)(m0 + cl) * Kd + kc * 8;
        brp[j2] = Bb + (size_t)(n0 + row) * Kd + kc * 8;
    }
    unsigned short* a_l = As + (wv << 6) * 8;
    unsigned short* b_l = Bs + (wv << 6) * 8;

    int fr = lane & 15, quad = lane >> 4, sw = fr & 7;
    int wm = (wv & 1) << 6, wn = (wv >> 1) << 6;

    f32x4 acc[4][4] = {};

    for (int k0 = 0; k0 < Kd; k0 += 64) {
        __syncthreads();
#pragma unroll
        for (int j2 = 0; j2 < 4; j2++) {
            gll16(a_l + j2 * 2048, arp[j2] + k0);
            gll16(b_l + j2 * 2048, brp[j2] + k0);
        }
        __syncthreads();
#pragma unroll
        for (int s = 0; s < 2; s++) {
            int off = (((s << 2) + quad) ^ sw) << 3;
            bf16x8 a[4], b[4];
#pragma unroll
            for (int tm = 0; tm < 4; tm++)
                a[tm] = *(const bf16x8*)&As[(wm + tm * 16 + fr) * 64 + off];
#pragma unroll
            for (int tn = 0; tn < 4; tn++)
                b[tn] = *(const bf16x8*)&Bs[(wn + tn * 16 + fr) * 64 + off];
#pragma unroll
            for (int tm = 0; tm < 4; tm++)
#pragma unroll
                for (int tn = 0; tn < 4; tn++)
                    acc[tm][tn] = __builtin_amdgcn_mfma_f32_16x16x32_bf16(a[tm], b[tn], acc[tm][tn], 0, 0, 0);
        }
    }
#pragma unroll
    for (int tm = 0; tm < 4; tm++)
#pragma unroll
        for (int r = 0; r < 4; r++) {
            int row = wm + tm * 16 + (quad << 2) + r;
            if (row < mcnt) {
                int tok; float w;
                if (gath) { tok = at[m0 + row]; w = aw[m0 + row]; }
                else      { tok = m0 + row;     w = 1.f; }
#pragma unroll
                for (int tn = 0; tn < 4; tn++)
                    atomicAdd(&out[(size_t)tok * DMODEL + n0 + wn + tn * 16 + fr],
                              w * acc[tm][tn][r]);
            }
        }
}

extern "C" void kernel_launch(void* const* d_in, const int* in_sizes, int n_in,
                              void* d_out, int out_size, void* d_ws, size_t ws_size,
                              hipStream_t stream) {
    (void)in_sizes; (void)n_in;
    const float* x  = (const float*)d_in[0];
    const float* rw = (const float*)d_in[1];
    const float* wg = (const float*)d_in[2];
    const float* wu = (const float*)d_in[3];
    const float* wd = (const float*)d_in[4];
    const float* sg = (const float*)d_in[5];
    const float* su = (const float*)d_in[6];
    const float* sd = (const float*)d_in[7];
    float* out = (float*)d_out;

    int* counts  = (int*)d_ws;
    int* offsets = counts + 8;
    int* cursors = counts + 16;
    int* ntiles  = counts + 24;
    int* tile_e  = counts + 32;          // 144
    int* tile_r  = tile_e + 144;         // 144
    int* topi    = tile_r + 144;         // 8192
    float* topw  = (float*)(topi + 8192);
    int* at      = (int*)(topw + 8192);
    float* aw    = (float*)(at + 8192);

    const size_t META = 262144;
    const size_t XB   = (size_t)NTOK * DMODEL * 2;    // 16,777,216
    unsigned short* xb = (unsigned short*)((char*)d_ws + META);
    char* pool = (char*)d_ws + META + XB;

    // pool layout (bf16 buffers), sizes in bytes
    const size_t SZ_WGT = 46137344;   // 8 x [1408,2048]
    const size_t SZ_SGT = 11534336;   // [2816,2048]
    const size_t SZ_H   = 23068672;   // [8192,1408] / [4096,2816]
    unsigned short* wgT = (unsigned short*)pool;
    unsigned short* wuT = (unsigned short*)(pool + SZ_WGT);
    unsigned short* sgT = (unsigned short*)(pool + 2 * SZ_WGT);
    unsigned short* suT = (unsigned short*)(pool + 2 * SZ_WGT + SZ_SGT);
    unsigned short* h_r = (unsigned short*)(pool + 2 * SZ_WGT + 2 * SZ_SGT);
    unsigned short* h_s = (unsigned short*)(pool + 2 * SZ_WGT + 2 * SZ_SGT + SZ_H);

    const size_t FULL2_NEED = META + XB + 2 * SZ_WGT + 2 * SZ_SGT + 2 * SZ_H
                              + SZ_WGT + SZ_SGT;          // ~236.2 MB
    bool full2 = ws_size >= FULL2_NEED;
    // FULL (178.5 MB, proven in round 3): wdT/sdT alias wgT/wuT, cvt after kg
    unsigned short* wdT = full2
        ? (unsigned short*)(pool + 2 * SZ_WGT + 2 * SZ_SGT + 2 * SZ_H)
        : wgT;
    unsigned short* sdT = full2
        ? (unsigned short*)(pool + 2 * SZ_WGT + 2 * SZ_SGT + 2 * SZ_H + SZ_WGT)
        : (unsigned short*)(pool + SZ_WGT);

    hipMemsetAsync(counts, 0, 32, stream);
    hipMemsetAsync(out, 0, (size_t)out_size * sizeof(float), stream);

    k_prep<<<dim3(PREP_GRID), 256, 0, stream>>>(
        x, rw, wg, wu, sg, su, xb, wgT, wuT, sgT, suT, topi, topw, counts);
    k_scan<<<1, 64, 0, stream>>>(counts, offsets, cursors, ntiles, tile_e, tile_r);
    k_fill<<<dim3(NTOK / 256), 256, 0, stream>>>(topi, topw, cursors, at, aw);

    if (full2) {
        k_main1<<<dim3(STRIPES * 21), 256, 0, stream>>>(
            xb, sgT, suT, wgT, wuT, wd, sd, wdT, sdT,
            tile_e, tile_r, offsets, counts, ntiles, at, h_s, h_r,
            KG_TOTAL, CVT1_TOTAL);
    } else {
        k_main1<<<dim3(KG_TOTAL), 256, 0, stream>>>(
            xb, sgT, suT, wgT, wuT, wd, sd, wdT, sdT,
            tile_e, tile_r, offsets, counts, ntiles, at, h_s, h_r,
            KG_TOTAL, 0);
        k_main1<<<dim3(CVT1_TOTAL), 256, 0, stream>>>(
            xb, sgT, suT, wgT, wuT, wd, sd, wdT, sdT,
            tile_e, tile_r, offsets, counts, ntiles, at, h_s, h_r,
            0, CVT1_TOTAL);
    }
    kd_all<<<dim3(KD_GRID), 256, 0, stream>>>(
        h_s, h_r, sdT, wdT, tile_e, tile_r, offsets, counts, ntiles, at, aw, out);
}